// Round 5
// baseline (60.919 us; speedup 1.0000x reference)
//
#include <hip/hip_runtime.h>
#include <hip/hip_cooperative_groups.h>
#include <cfloat>

namespace cg = cooperative_groups;

#define TPB 512
#define PPB 4                 // trajectory points per block
#define NWAVES (TPB / 64)

// ---------------------------------------------------------------------------
// One cooperative kernel, one graph node, no atomics, no memset.
// Block b owns points [b*PPB, b*PPB+PPB). All 512 threads stride the full
// obstacle array (float4 = 2 obstacles). Shifted-distance trick:
//   |p-o|^2 - |p|^2 = |o|^2 - 2 p.o   (per-point constant shift, order-safe)
// so each pair costs 2 FMA + fmed3 + fmin. Shfl butterfly + LDS merge give
// the block's two-smallest per point; 4 threads compute loss terms; block
// partial goes to bsum[b] (plain store). grid.sync(); block 0 reduces and
// writes out[0] (single writer -> no zeroing needed).
// ---------------------------------------------------------------------------
__global__ __launch_bounds__(TPB) void traj_coop(
        const float2* __restrict__ traj,
        const float4* __restrict__ obs4,
        float* __restrict__ bsum,       // [gridDim.x]
        float* __restrict__ out,
        int N, int M) {
    const float HINV = 1.0f / 1024.0f;
    const int t = threadIdx.x;
    const int pbase = blockIdx.x * PPB;

    __shared__ float2 lm[NWAVES][PPB];
    __shared__ float contrib[PPB];
    __shared__ float wsum[NWAVES];

    float tx[PPB], ty[PPB], m1[PPB], m2[PPB];
#pragma unroll
    for (int p = 0; p < PPB; ++p) {
        int idx = pbase + p;
        float2 tp = traj[idx < N ? idx : N - 1];
        float px = (idx < N) ? tp.x * HINV : 1.0e6f;
        float py = (idx < N) ? tp.y * HINV : 1.0e6f;
        tx[p] = -2.0f * px;
        ty[p] = -2.0f * py;
        m1[p] = FLT_MAX;
        m2[p] = FLT_MAX;
    }

    // ---- pairwise pass (shifted squared distances) ----
    const int npairs = M >> 1;
#pragma unroll 4
    for (int k = t; k < npairs; k += TPB) {
        float4 o = obs4[k];
        float o2a = __builtin_fmaf(o.x, o.x, o.y * o.y);
        float o2b = __builtin_fmaf(o.z, o.z, o.w * o.w);
#pragma unroll
        for (int p = 0; p < PPB; ++p) {
            float da = __builtin_fmaf(tx[p], o.x,
                        __builtin_fmaf(ty[p], o.y, o2a));
            float n2 = __builtin_amdgcn_fmed3f(da, m1[p], m2[p]);
            m1[p] = fminf(m1[p], da);
            m2[p] = n2;
            float db = __builtin_fmaf(tx[p], o.z,
                        __builtin_fmaf(ty[p], o.w, o2b));
            n2 = __builtin_amdgcn_fmed3f(db, m1[p], m2[p]);
            m1[p] = fminf(m1[p], db);
            m2[p] = n2;
        }
    }
    if ((M & 1) && t == 0) {               // odd-M tail (M even in practice)
        float2 o = ((const float2*)obs4)[M - 1];
        float o2 = __builtin_fmaf(o.x, o.x, o.y * o.y);
#pragma unroll
        for (int p = 0; p < PPB; ++p) {
            float d2 = __builtin_fmaf(tx[p], o.x,
                        __builtin_fmaf(ty[p], o.y, o2));
            float n2 = __builtin_amdgcn_fmed3f(d2, m1[p], m2[p]);
            m1[p] = fminf(m1[p], d2);
            m2[p] = n2;
        }
    }

    // ---- in-wave butterfly merge of (m1,m2) pairs ----
#pragma unroll
    for (int s = 1; s < 64; s <<= 1) {
#pragma unroll
        for (int p = 0; p < PPB; ++p) {
            float o1 = __shfl_xor(m1[p], s, 64);
            float o2 = __shfl_xor(m2[p], s, 64);
            float hi = fmaxf(m1[p], o1);
            m1[p] = fminf(m1[p], o1);
            m2[p] = fminf(fminf(m2[p], o2), hi);
        }
    }

    // ---- cross-wave merge via LDS (block-local) ----
    const int wave = t >> 6;
    const int lane = t & 63;
    if (lane == 0) {
#pragma unroll
        for (int p = 0; p < PPB; ++p) lm[wave][p] = make_float2(m1[p], m2[p]);
    }
    __syncthreads();

    if (t < PPB) {
        const int p = t;
        const int i = pbase + p;
        float c = 0.0f;
        if (i < N) {
            float a1 = FLT_MAX, a2 = FLT_MAX;
#pragma unroll
            for (int w = 0; w < NWAVES; ++w) {
                float2 b = lm[w][p];
                float hi = fmaxf(a1, b.x);
                a1 = fminf(a1, b.x);
                a2 = fminf(fminf(a2, b.y), hi);
            }
            float2 tp = traj[i];
            float px = tp.x * HINV, py = tp.y * HINV;
            float pp = __builtin_fmaf(px, px, py * py);   // undo the shift

            float d_obs = sqrtf(a1 + pp + 1e-6f);
            float d_sec = sqrtf(a2 + pp + 1e-6f);
            float d_vor = 0.5f * (d_sec - d_obs);
            float r = fmaxf(0.05f - d_obs, 0.0f);
            c = 1000.0f * r * r;             // obstacle term (weight folded)
            if (d_obs <= 0.05f) {
                float q = d_obs - 0.05f;
                float rho = (0.1f / (0.1f + d_obs))
                          * (d_vor / (d_obs + d_vor + 1e-6f))
                          * (q * q) / (0.05f * 0.05f);
                c += rho;                    // voronoi term
            }

            if (i <= N - 3) {                // balance / curvature / steering
                float2 t0 = traj[i];
                float2 t1 = traj[i + 1];
                float2 t2 = traj[i + 2];
                float sx = t2.x - 2.0f * t1.x + t0.x;
                float sy = t2.y - 2.0f * t1.y + t0.y;
                c += sx * sx + sy * sy;
                float d0x = t1.x - t0.x, d0y = t1.y - t0.y;
                float d1x = t2.x - t1.x, d1y = t2.y - t1.y;
                float th0 = atan2f(d0y, d0x);
                float th1 = atan2f(d1y, d1x);
                float dth = th1 - th0;
                const float PI_F = 3.14159265358979323846f;
                if (dth > PI_F) dth -= 2.0f * PI_F;
                else if (dth < -PI_F) dth += 2.0f * PI_F;
                float adth = fabsf(dth);
                float seg = sqrtf(d0x * d0x + d0y * d0y);
                float kappa = adth / (seg + 1e-6f);
                float rc = fmaxf(kappa - 0.04f, 0.0f);
                float rs = fmaxf(adth - 0.04f, 0.0f);
                c += rc * rc + rs * rs;
            }
        }
        contrib[p] = c;
    }
    __syncthreads();

    if (t == 0) {
        float s = 0.0f;
#pragma unroll
        for (int p = 0; p < PPB; ++p) s += contrib[p];
        bsum[blockIdx.x] = s;
    }

    // ---- grid-wide barrier, then single-writer final reduction ----
    cg::this_grid().sync();

    if (blockIdx.x == 0) {
        const int G = gridDim.x;
        float v = 0.0f;
        for (int j = t; j < G; j += TPB) v += bsum[j];
#pragma unroll
        for (int s = 32; s > 0; s >>= 1) v += __shfl_down(v, s, 64);
        if (lane == 0) wsum[wave] = v;
        __syncthreads();
        if (t == 0) {
            float tot = 0.0f;
#pragma unroll
            for (int w = 0; w < NWAVES; ++w) tot += wsum[w];
            out[0] = tot;
        }
    }
}

extern "C" void kernel_launch(void* const* d_in, const int* in_sizes, int n_in,
                              void* d_out, int out_size, void* d_ws, size_t ws_size,
                              hipStream_t stream) {
    const float2* traj = (const float2*)d_in[0];
    const float4* obs4 = (const float4*)d_in[1];
    float* out  = (float*)d_out;
    float* bsum = (float*)d_ws;
    int N = in_sizes[0] / 2;
    int M = in_sizes[1] / 2;

    int grid = (N + PPB - 1) / PPB;        // 512 blocks for N=2048
    void* args[] = {(void*)&traj, (void*)&obs4, (void*)&bsum,
                    (void*)&out, (void*)&N, (void*)&M};
    hipLaunchCooperativeKernel((void*)traj_coop, dim3(grid), dim3(TPB),
                               args, 0, stream);
}

// Round 6
// 14.251 us; speedup vs baseline: 4.2746x; 4.2746x over previous
//
#include <hip/hip_runtime.h>
#include <cfloat>

#define TPB 512
#define PPB 4                 // trajectory points per block
#define NWAVES (TPB / 64)

// ---------------------------------------------------------------------------
// K1: block b owns points [b*PPB, b*PPB+PPB). All 512 threads stride the
// obstacle array (float4 = 2 obstacles), shifted-distance trick:
//   |p-o|^2 - |p|^2 = |o|^2 - 2 p.o   (per-point constant shift, order-safe)
// -> 2 FMA + fmed3 + fmin per pair. Shfl butterfly + LDS merge produce the
// block's two-smallest per point; PPB threads compute loss terms; block
// partial goes to bsum[b] as a PLAIN STORE (written unconditionally every
// call -> no zeroing, no atomics, no fences).
// ---------------------------------------------------------------------------
__global__ __launch_bounds__(TPB) void traj_part(
        const float2* __restrict__ traj,
        const float4* __restrict__ obs4,
        float* __restrict__ bsum,       // [gridDim.x]
        int N, int M) {
    const float HINV = 1.0f / 1024.0f;
    const int t = threadIdx.x;
    const int pbase = blockIdx.x * PPB;

    __shared__ float2 lm[NWAVES][PPB];
    __shared__ float contrib[PPB];

    float tx[PPB], ty[PPB], m1[PPB], m2[PPB];
#pragma unroll
    for (int p = 0; p < PPB; ++p) {
        int idx = pbase + p;
        float2 tp = traj[idx < N ? idx : N - 1];
        float px = (idx < N) ? tp.x * HINV : 1.0e6f;
        float py = (idx < N) ? tp.y * HINV : 1.0e6f;
        tx[p] = -2.0f * px;
        ty[p] = -2.0f * py;
        m1[p] = FLT_MAX;
        m2[p] = FLT_MAX;
    }

    // ---- pairwise pass (shifted squared distances) ----
    const int npairs = M >> 1;
#pragma unroll 4
    for (int k = t; k < npairs; k += TPB) {
        float4 o = obs4[k];
        float o2a = __builtin_fmaf(o.x, o.x, o.y * o.y);
        float o2b = __builtin_fmaf(o.z, o.z, o.w * o.w);
#pragma unroll
        for (int p = 0; p < PPB; ++p) {
            float da = __builtin_fmaf(tx[p], o.x,
                        __builtin_fmaf(ty[p], o.y, o2a));
            float n2 = __builtin_amdgcn_fmed3f(da, m1[p], m2[p]);
            m1[p] = fminf(m1[p], da);
            m2[p] = n2;
            float db = __builtin_fmaf(tx[p], o.z,
                        __builtin_fmaf(ty[p], o.w, o2b));
            n2 = __builtin_amdgcn_fmed3f(db, m1[p], m2[p]);
            m1[p] = fminf(m1[p], db);
            m2[p] = n2;
        }
    }
    if ((M & 1) && t == 0) {               // odd-M tail (M even in practice)
        float2 o = ((const float2*)obs4)[M - 1];
        float o2 = __builtin_fmaf(o.x, o.x, o.y * o.y);
#pragma unroll
        for (int p = 0; p < PPB; ++p) {
            float d2 = __builtin_fmaf(tx[p], o.x,
                        __builtin_fmaf(ty[p], o.y, o2));
            float n2 = __builtin_amdgcn_fmed3f(d2, m1[p], m2[p]);
            m1[p] = fminf(m1[p], d2);
            m2[p] = n2;
        }
    }

    // ---- in-wave butterfly merge of (m1,m2) pairs ----
#pragma unroll
    for (int s = 1; s < 64; s <<= 1) {
#pragma unroll
        for (int p = 0; p < PPB; ++p) {
            float o1 = __shfl_xor(m1[p], s, 64);
            float o2 = __shfl_xor(m2[p], s, 64);
            float hi = fmaxf(m1[p], o1);
            m1[p] = fminf(m1[p], o1);
            m2[p] = fminf(fminf(m2[p], o2), hi);
        }
    }

    // ---- cross-wave merge via LDS (block-local) ----
    const int wave = t >> 6;
    const int lane = t & 63;
    if (lane == 0) {
#pragma unroll
        for (int p = 0; p < PPB; ++p) lm[wave][p] = make_float2(m1[p], m2[p]);
    }
    __syncthreads();

    if (t < PPB) {
        const int p = t;
        const int i = pbase + p;
        float c = 0.0f;
        if (i < N) {
            float a1 = FLT_MAX, a2 = FLT_MAX;
#pragma unroll
            for (int w = 0; w < NWAVES; ++w) {
                float2 b = lm[w][p];
                float hi = fmaxf(a1, b.x);
                a1 = fminf(a1, b.x);
                a2 = fminf(fminf(a2, b.y), hi);
            }
            float2 tp = traj[i];
            float px = tp.x * HINV, py = tp.y * HINV;
            float pp = __builtin_fmaf(px, px, py * py);   // undo the shift

            float d_obs = sqrtf(a1 + pp + 1e-6f);
            float d_sec = sqrtf(a2 + pp + 1e-6f);
            float d_vor = 0.5f * (d_sec - d_obs);
            float r = fmaxf(0.05f - d_obs, 0.0f);
            c = 1000.0f * r * r;             // obstacle term (weight folded)
            if (d_obs <= 0.05f) {
                float q = d_obs - 0.05f;
                float rho = (0.1f / (0.1f + d_obs))
                          * (d_vor / (d_obs + d_vor + 1e-6f))
                          * (q * q) / (0.05f * 0.05f);
                c += rho;                    // voronoi term
            }

            if (i <= N - 3) {                // balance / curvature / steering
                float2 t0 = traj[i];
                float2 t1 = traj[i + 1];
                float2 t2 = traj[i + 2];
                float sx = t2.x - 2.0f * t1.x + t0.x;
                float sy = t2.y - 2.0f * t1.y + t0.y;
                c += sx * sx + sy * sy;
                float d0x = t1.x - t0.x, d0y = t1.y - t0.y;
                float d1x = t2.x - t1.x, d1y = t2.y - t1.y;
                float th0 = atan2f(d0y, d0x);
                float th1 = atan2f(d1y, d1x);
                float dth = th1 - th0;
                const float PI_F = 3.14159265358979323846f;
                if (dth > PI_F) dth -= 2.0f * PI_F;
                else if (dth < -PI_F) dth += 2.0f * PI_F;
                float adth = fabsf(dth);
                float seg = sqrtf(d0x * d0x + d0y * d0y);
                float kappa = adth / (seg + 1e-6f);
                float rc = fmaxf(kappa - 0.04f, 0.0f);
                float rs = fmaxf(adth - 0.04f, 0.0f);
                c += rc * rc + rs * rs;
            }
        }
        contrib[p] = c;
    }
    __syncthreads();

    if (t == 0) {
        float s = 0.0f;
#pragma unroll
        for (int p = 0; p < PPB; ++p) s += contrib[p];
        bsum[blockIdx.x] = s;              // plain store, unconditional
    }
}

// ---------------------------------------------------------------------------
// K2: one block reduces G partials and writes out[0] (single writer, no
// zeroing needed).
// ---------------------------------------------------------------------------
__global__ __launch_bounds__(TPB) void traj_reduce(
        const float* __restrict__ bsum,
        float* __restrict__ out,
        int G) {
    const int t = threadIdx.x;
    float v = 0.0f;
    for (int j = t; j < G; j += TPB) v += bsum[j];
#pragma unroll
    for (int s = 32; s > 0; s >>= 1) v += __shfl_down(v, s, 64);
    __shared__ float wsum[NWAVES];
    const int wave = t >> 6;
    const int lane = t & 63;
    if (lane == 0) wsum[wave] = v;
    __syncthreads();
    if (t == 0) {
        float tot = 0.0f;
#pragma unroll
        for (int w = 0; w < NWAVES; ++w) tot += wsum[w];
        out[0] = tot;
    }
}

extern "C" void kernel_launch(void* const* d_in, const int* in_sizes, int n_in,
                              void* d_out, int out_size, void* d_ws, size_t ws_size,
                              hipStream_t stream) {
    const float2* traj = (const float2*)d_in[0];
    const float4* obs4 = (const float4*)d_in[1];
    float* out  = (float*)d_out;
    float* bsum = (float*)d_ws;
    int N = in_sizes[0] / 2;
    int M = in_sizes[1] / 2;

    int grid = (N + PPB - 1) / PPB;        // 512 blocks for N=2048
    traj_part<<<grid, TPB, 0, stream>>>(traj, obs4, bsum, N, M);
    traj_reduce<<<1, TPB, 0, stream>>>(bsum, out, grid);
}